// Round 5
// baseline (442.849 us; speedup 1.0000x reference)
//
#include <hip/hip_runtime.h>
#include <hip/hip_bf16.h>
#include <stdint.h>

// B=4, Sq=Skv=1024, H=16, D=64, DM=1024, MRP=32
static constexpr int B_ = 4, S_ = 1024, H_ = 16, D_ = 64, DM_ = 1024;
// sqrt(64) * 1024^0.25 in fp32 exactly as np computes it
static constexpr float SF_ = 45.254833221435546875f;
static constexpr float RCP_SF_ = 1.0f / SF_;

typedef unsigned short u16;
typedef __attribute__((ext_vector_type(8))) short bf16x8;
typedef __attribute__((ext_vector_type(4))) float f32x4;

#define MFMA_BF16 __builtin_amdgcn_mfma_f32_16x16x32_bf16

typedef const __attribute__((address_space(1))) void CGV;
typedef __attribute__((address_space(3))) void LDSV;
__device__ __forceinline__ void gload16(const void* g, void* l) {
  __builtin_amdgcn_global_load_lds((CGV*)g, (LDSV*)l, 16, 0, 0);
}

__device__ __forceinline__ float slot_scale(const unsigned* s) {
  return __uint_as_float(*s) / 127.0f + 1e-8f;  // absmax/127 + 1e-8, reference order
}
__device__ __forceinline__ float quantf(float x, float s) {
  return fminf(fmaxf(rintf(x / s), -127.f), 127.f);  // RNE like jnp.round
}
__device__ __forceinline__ u16 f2b(float x) {  // float -> bf16 (HIP conversion)
  union { __hip_bfloat16 h; u16 u; } cv;
  cv.h = __float2bfloat16(x);
  return cv.u;
}
__device__ __forceinline__ float b2f(u16 u) { return __uint_as_float((unsigned)u << 16); }
__device__ __forceinline__ u16 qb16(float x, float s) { return f2b(quantf(x, s)); }
__device__ __forceinline__ float div_sf(float t2) {
  // correctly-rounded t2/SF_ (Markstein)
  float q0 = t2 * RCP_SF_;
  float r = fmaf(-SF_, q0, t2);
  return fmaf(r, RCP_SF_, q0);
}

__global__ void zero_slots_kernel(unsigned* slots) {
  if (threadIdx.x < 16) slots[threadIdx.x] = 0u;
}

struct Ptr6 { const float* p[6]; int n4[6]; };

__global__ __launch_bounds__(256) void absmax6_kernel(Ptr6 a, unsigned* __restrict__ slots) {
  const int y = blockIdx.y;
  const float4* x4 = (const float4*)a.p[y];
  const int n4 = a.n4[y];
  float m = 0.f;
  for (int i = blockIdx.x * 256 + threadIdx.x; i < n4; i += gridDim.x * 256) {
    float4 v = x4[i];
    m = fmaxf(m, fmaxf(fmaxf(fabsf(v.x), fabsf(v.y)), fmaxf(fabsf(v.z), fabsf(v.w))));
  }
#pragma unroll
  for (int off = 32; off; off >>= 1) m = fmaxf(m, __shfl_xor(m, off));
  if ((threadIdx.x & 63) == 0) atomicMax(slots + y, __float_as_uint(m));
}

__device__ __forceinline__ void quant_body(const float* __restrict__ x, int n8, float s,
                                           u16* __restrict__ out) {
  for (int i = blockIdx.x * 256 + threadIdx.x; i < n8; i += gridDim.x * 256) {
    float4 v0 = *((const float4*)x + 2 * (size_t)i);
    float4 v1 = *((const float4*)x + 2 * (size_t)i + 1);
    int4 o;
    o.x = (int)qb16(v0.x, s) | ((int)qb16(v0.y, s) << 16);
    o.y = (int)qb16(v0.z, s) | ((int)qb16(v0.w, s) << 16);
    o.z = (int)qb16(v1.x, s) | ((int)qb16(v1.y, s) << 16);
    o.w = (int)qb16(v1.z, s) | ((int)qb16(v1.w, s) << 16);
    *((int4*)out + i) = o;
  }
}

__global__ __launch_bounds__(256) void quantize_bf16_kernel(const float* __restrict__ x, int n8,
                                                            const unsigned* __restrict__ slot,
                                                            u16* __restrict__ out) {
  quant_body(x, n8, slot_scale(slot), out);
}

__global__ __launch_bounds__(256) void quantize2_kernel(const float* __restrict__ x0,
                                                        const float* __restrict__ x1,
                                                        u16* __restrict__ o0, u16* __restrict__ o1,
                                                        const unsigned* __restrict__ slots, int n8) {
  const int y = blockIdx.y;
  quant_body(y ? x1 : x0, n8, slot_scale(slots + y), y ? o1 : o0);
}

// Quantize v (float [B*S][DM]) and write TRANSPOSED per-(b,h): vT[((b*16+h)*64 + d)][kv]
__global__ __launch_bounds__(256) void quantizeT_v_kernel(const float* __restrict__ vf,
                                                          const unsigned* __restrict__ slot,
                                                          u16* __restrict__ vT) {
  __shared__ u16 t[64][72];
  const float s = slot_scale(slot);
  const int bt = blockIdx.x;           // b*16 + kvtile
  const int h = blockIdx.y;
  const int b = bt >> 4, kt = bt & 15;
  const int tid = threadIdx.x;
  const int row = tid >> 2, seg = (tid & 3) * 16;  // kv-local row, 16 d-cols
  const float* src = &vf[((size_t)(b * S_) + kt * 64 + row) * DM_ + h * 64 + seg];
  float4 v0 = *(const float4*)src;
  float4 v1 = *(const float4*)(src + 4);
  float4 v2 = *(const float4*)(src + 8);
  float4 v3 = *(const float4*)(src + 12);
  t[seg + 0][row] = qb16(v0.x, s);  t[seg + 1][row] = qb16(v0.y, s);
  t[seg + 2][row] = qb16(v0.z, s);  t[seg + 3][row] = qb16(v0.w, s);
  t[seg + 4][row] = qb16(v1.x, s);  t[seg + 5][row] = qb16(v1.y, s);
  t[seg + 6][row] = qb16(v1.z, s);  t[seg + 7][row] = qb16(v1.w, s);
  t[seg + 8][row] = qb16(v2.x, s);  t[seg + 9][row] = qb16(v2.y, s);
  t[seg + 10][row] = qb16(v2.z, s); t[seg + 11][row] = qb16(v2.w, s);
  t[seg + 12][row] = qb16(v3.x, s); t[seg + 13][row] = qb16(v3.y, s);
  t[seg + 14][row] = qb16(v3.z, s); t[seg + 15][row] = qb16(v3.w, s);
  __syncthreads();
  const int d = tid >> 2, s2 = (tid & 3) * 16;
  u16* dst = &vT[((size_t)(b * 16 + h) * 64 + d) * (size_t)S_ + kt * 64 + s2];
  *(int4*)dst = *(const int4*)&t[d][s2];
  *(int4*)(dst + 8) = *(const int4*)&t[d][s2 + 8];
}

// Quantize weight [K,N] -> transposed bf16 [N][K], 4 weights batched via z
struct W4 { const float* w[4]; u16* wt[4]; };
__global__ __launch_bounds__(256) void quantW4_kernel(W4 a, const unsigned* __restrict__ slots) {
  __shared__ u16 t[64][72];
  const int z = blockIdx.z;
  const float* w = a.w[z];
  u16* wt = a.wt[z];
  const float s = slot_scale(slots + 2 + z);
  const int k0 = blockIdx.y * 64, n0 = blockIdx.x * 64;
  const int tid = threadIdx.x;
#pragma unroll
  for (int rr = 0; rr < 4; rr++) {
    const int row = (tid >> 4) + rr * 16;  // k
    const int col = (tid & 15) * 4;        // n
    float4 v = *(const float4*)&w[(size_t)(k0 + row) * DM_ + n0 + col];
    t[col + 0][row] = qb16(v.x, s);
    t[col + 1][row] = qb16(v.y, s);
    t[col + 2][row] = qb16(v.z, s);
    t[col + 3][row] = qb16(v.w, s);
  }
  __syncthreads();
  const int nr = tid >> 2, kc = (tid & 3) * 16;
  *(int4*)&wt[(size_t)(n0 + nr) * DM_ + k0 + kc] = *(const int4*)&t[nr][kc];
  *(int4*)&wt[(size_t)(n0 + nr) * DM_ + k0 + kc + 8] = *(const int4*)&t[nr][kc + 8];
}

// C[M,N] = exact-int (A[M,K] . Bt[N,K]^T) * (sA*sB) + bias[N].  M=4096, N=K=1024.
__global__ __launch_bounds__(256) void gemm128_kernel(
    const u16* __restrict__ A, const u16* __restrict__ Bt,
    const unsigned* __restrict__ slotA, const unsigned* __restrict__ slotB,
    const float* __restrict__ bias, float* __restrict__ C,
    unsigned* __restrict__ amax_out) {
  __shared__ u16 As[2][128][64];
  __shared__ u16 Bs[2][64][64];
  const int N = DM_, K = DM_;
  const int id = blockIdx.x;                       // 0..511
  const int lin = (id & 7) * 64 + (id >> 3);       // XCD-contiguous m-panels
  const int by = lin >> 4, bx = lin & 15;
  const int m0 = by * 128, n0 = bx * 64;
  const int tid = threadIdx.x, w = tid >> 6, lane = tid & 63;
  const int c = lane & 15, g = lane >> 4;
  const int wr = w >> 1, wc = w & 1;
  const int lr = lane >> 3, lc = lane & 7;
  const int schunk = (lc ^ lr) << 3;

  f32x4 acc[4][2] = {};

  auto stage = [&](int buf, int kc) {
#pragma unroll
    for (int p = 0; p < 4; ++p) {
      const int r0 = w * 32 + p * 8;
      gload16(&A[(size_t)(m0 + r0 + lr) * K + kc + schunk], &As[buf][r0][0]);
    }
#pragma unroll
    for (int p = 0; p < 2; ++p) {
      const int r0 = w * 16 + p * 8;
      gload16(&Bt[(size_t)(n0 + r0 + lr) * K + kc + schunk], &Bs[buf][r0][0]);
    }
  };

  stage(0, 0);
  __syncthreads();
  for (int kt = 0; kt < 16; ++kt) {
    const int buf = kt & 1;
    if (kt < 15) stage(buf ^ 1, (kt + 1) * 64);
#pragma unroll
    for (int ks = 0; ks < 2; ++ks) {
      const int rswz = ((ks * 4 + g) ^ (c & 7)) << 3;
      bf16x8 b0 = *(const bf16x8*)&Bs[buf][wc * 32 + c][rswz];
      bf16x8 b1 = *(const bf16x8*)&Bs[buf][wc * 32 + 16 + c][rswz];
#pragma unroll
      for (int i = 0; i < 4; ++i) {
        bf16x8 av = *(const bf16x8*)&As[buf][wr * 64 + i * 16 + c][rswz];
        acc[i][0] = MFMA_BF16(av, b0, acc[i][0], 0, 0, 0);
        acc[i][1] = MFMA_BF16(av, b1, acc[i][1], 0, 0, 0);
      }
    }
    __syncthreads();
  }

  const float sAB = slot_scale(slotA) * slot_scale(slotB);
  float am = 0.f;
#pragma unroll
  for (int i = 0; i < 4; ++i)
#pragma unroll
    for (int j = 0; j < 2; ++j)
#pragma unroll
      for (int reg = 0; reg < 4; ++reg) {
        const int m = m0 + wr * 64 + i * 16 + 4 * g + reg;
        const int nn = n0 + wc * 32 + j * 16 + c;
        const float val = __fadd_rn(__fmul_rn(acc[i][j][reg], sAB), bias[nn]);
        C[(size_t)m * N + nn] = val;
        am = fmaxf(am, fabsf(val));
      }
  if (amax_out) {
#pragma unroll
    for (int off = 32; off; off >>= 1) am = fmaxf(am, __shfl_xor(am, off));
    if (lane == 0) atomicMax(amax_out, __float_as_uint(am));
  }
}

// ---- attention pass 1: exact row max -> Mg[(b*16+h)*1024 + q] (post-division)
__global__ __launch_bounds__(256, 4) void attn_max_kernel(
    const u16* __restrict__ qb_, const u16* __restrict__ kb_,
    const unsigned* __restrict__ slots, const float* __restrict__ rel,
    float* __restrict__ Mg) {
  __shared__ u16 Ks[2][64][64];
  __shared__ float biasT[68];

  const int id = blockIdx.x;
  const int rX = id & 7, jX = id >> 3;
  const int qt = jX & 15, gbh = (jX >> 4) * 8 + rX;
  const int h = gbh & 15, b = gbh >> 4;

  const int tid = threadIdx.x;
  const int w = tid >> 6, lane = tid & 63;
  const int c = lane & 15, g = lane >> 4;
  const int lr = lane >> 3, lc = lane & 7;
  const int schunk = (lc ^ lr) << 3;

  const float sqk = slot_scale(slots + 6) * slot_scale(slots + 7);
  if (tid < 65) biasT[tid] = rel[tid * D_ + h];

  const int qbase = qt * 64 + w * 16;
  const size_t qrow = ((size_t)(b * S_) + qbase + c) * DM_ + h * 64;
  const bf16x8 qA0 = *(const bf16x8*)&qb_[qrow + g * 8];
  const bf16x8 qA1 = *(const bf16x8*)&qb_[qrow + 32 + g * 8];

  const size_t kvbase = (size_t)(b * S_) * DM_ + h * 64;

  auto stageK = [&](int buf, int ch) {
#pragma unroll
    for (int p = 0; p < 2; ++p) {
      const int r0 = w * 16 + p * 8;
      gload16(&kb_[kvbase + (size_t)(ch * 64 + r0 + lr) * DM_ + schunk], &Ks[buf][r0][0]);
    }
  };

  float m2[4] = {-3.4e38f, -3.4e38f, -3.4e38f, -3.4e38f};
  stageK(0, 0);
  __syncthreads();
  const float b_lo = biasT[0], b_hi = biasT[64];
  for (int ch = 0; ch < 16; ++ch) {
    const int buf = ch & 1;
    if (ch < 15) stageK(buf ^ 1, ch + 1);
#pragma unroll
    for (int t = 0; t < 4; ++t) {
      f32x4 sacc = {0.f, 0.f, 0.f, 0.f};
      const int kr = t * 16 + c, sw = c & 7;
      bf16x8 k0 = *(const bf16x8*)&Ks[buf][kr][(g ^ sw) << 3];
      bf16x8 k1 = *(const bf16x8*)&Ks[buf][kr][((4 + g) ^ sw) << 3];
      sacc = MFMA_BF16(qA0, k0, sacc, 0, 0, 0);
      sacc = MFMA_BF16(qA1, k1, sacc, 0, 0, 0);
      const int kv0 = ch * 64 + t * 16;
      float bb[4];
      if (kv0 >= qbase + 47) {
        bb[0] = bb[1] = bb[2] = bb[3] = b_lo;
      } else if (qbase >= kv0 + 47) {
        bb[0] = bb[1] = bb[2] = bb[3] = b_hi;
      } else {
        const int jg = kv0 + c;
#pragma unroll
        for (int reg = 0; reg < 4; ++reg) {
          int dp = qbase + 4 * g + reg - jg + 32;
          dp = dp < 0 ? 0 : (dp > 64 ? 64 : dp);
          bb[reg] = biasT[dp];
        }
      }
#pragma unroll
      for (int reg = 0; reg < 4; ++reg)
        m2[reg] = fmaxf(m2[reg], __fadd_rn(__fmul_rn(sacc[reg], sqk), bb[reg]));
    }
    __syncthreads();
  }
#pragma unroll
  for (int off = 1; off <= 8; off <<= 1)
#pragma unroll
    for (int reg = 0; reg < 4; ++reg) m2[reg] = fmaxf(m2[reg], __shfl_xor(m2[reg], off));
  if (c == 0) {
    float* mdst = &Mg[(size_t)(b * 16 + h) * S_ + qbase + 4 * g];
#pragma unroll
    for (int reg = 0; reg < 4; ++reg) mdst[reg] = div_sf(m2[reg]);  // monotone => exact
  }
}

// ---- attention pass 2: exp (hw), 3-way bf16 split, PV MFMA. Single-buffer K/V,
// 4 blocks/CU (LDS ~34KB, VGPR capped 128).
__global__ __launch_bounds__(256, 4) void attn_av_kernel(
    const u16* __restrict__ qb_, const u16* __restrict__ kb_, const u16* __restrict__ vTb_,
    const unsigned* __restrict__ slots, const float* __restrict__ rel,
    const float* __restrict__ Mg, float* __restrict__ ao,
    unsigned* __restrict__ amax_out) {
  __shared__ u16 Ks[64][64];
  __shared__ u16 Vs[64][64];
  __shared__ float Pf[4][16][68];
  __shared__ float biasT[68];

  const int id = blockIdx.x;
  const int rX = id & 7, jX = id >> 3;
  const int qt = jX & 15, gbh = (jX >> 4) * 8 + rX;
  const int h = gbh & 15, b = gbh >> 4;

  const int tid = threadIdx.x;
  const int w = tid >> 6, lane = tid & 63;
  const int c = lane & 15, g = lane >> 4;
  const int lr = lane >> 3, lc = lane & 7;
  const int schunk = (lc ^ lr) << 3;

  const float sqk = slot_scale(slots + 6) * slot_scale(slots + 7);
  const float sv = slot_scale(slots + 8);
  if (tid < 65) biasT[tid] = rel[tid * D_ + h];

  const int qbase = qt * 64 + w * 16;
  const size_t qrow = ((size_t)(b * S_) + qbase + c) * DM_ + h * 64;
  const bf16x8 qA0 = *(const bf16x8*)&qb_[qrow + g * 8];
  const bf16x8 qA1 = *(const bf16x8*)&qb_[qrow + 32 + g * 8];
  const float4 Mv = *(const float4*)&Mg[(size_t)(b * 16 + h) * S_ + qbase + 4 * g];
  const float M[4] = {Mv.x, Mv.y, Mv.z, Mv.w};

  const size_t kvbase = (size_t)(b * S_) * DM_ + h * 64;
  const size_t vtbase = (size_t)(b * 16 + h) * 64 * (size_t)S_;

  f32x4 oacc[4] = {};
  float ls[4] = {0.f, 0.f, 0.f, 0.f};
  float b_lo = 0.f, b_hi = 0.f;

  for (int ch = 0; ch < 16; ++ch) {
    __syncthreads();   // waves done reading Ks/Vs (and, first iter, biasT visible)
    if (ch == 0) { b_lo = biasT[0]; b_hi = biasT[64]; }
#pragma unroll
    for (int p = 0; p < 2; ++p) {
      const int r0 = w * 16 + p * 8;
      gload16(&kb_[kvbase + (size_t)(ch * 64 + r0 + lr) * DM_ + schunk], &Ks[r0][0]);
      gload16(&vTb_[vtbase + (size_t)(r0 + lr) * S_ + ch * 64 + schunk], &Vs[r0][0]);
    }
    __syncthreads();   // staged (barrier drains vmcnt)
#pragma unroll
    for (int t = 0; t < 4; ++t) {
      f32x4 sacc = {0.f, 0.f, 0.f, 0.f};
      const int kr = t * 16 + c, sw = c & 7;
      bf16x8 k0 = *(const bf16x8*)&Ks[kr][(g ^ sw) << 3];
      bf16x8 k1 = *(const bf16x8*)&Ks[kr][((4 + g) ^ sw) << 3];
      sacc = MFMA_BF16(qA0, k0, sacc, 0, 0, 0);
      sacc = MFMA_BF16(qA1, k1, sacc, 0, 0, 0);
      const int kv0 = ch * 64 + t * 16;
      float bb[4];
      if (kv0 >= qbase + 47) {
        bb[0] = bb[1] = bb[2] = bb[3] = b_lo;
      } else if (qbase >= kv0 + 47) {
        bb[0] = bb[1] = bb[2] = bb[3] = b_hi;
      } else {
        const int jg = kv0 + c;
#pragma unroll
        for (int reg = 0; reg < 4; ++reg) {
          int dp = qbase + 4 * g + reg - jg + 32;
          dp = dp < 0 ? 0 : (dp > 64 ? 64 : dp);
          bb[reg] = biasT[dp];
        }
      }
      float* pw = &Pf[w][4 * g][t * 16 + c];
#pragma unroll
      for (int reg = 0; reg < 4; ++reg) {
        const float sc = div_sf(__fadd_rn(__fmul_rn(sacc[reg], sqk), bb[reg]));
        const float e = __expf(sc - M[reg]);   // hw v_exp_f32 (~2 ULP)
        ls[reg] += e;
        pw[reg * 68] = e;
      }
    }
    // PV: read own wave's P rows, split 3-way bf16, MFMA against Vs (d-major)
#pragma unroll
    for (int ks = 0; ks < 2; ++ks) {
      const float* pr = &Pf[w][c][ks * 32 + g * 8];
      float4 e0 = *(const float4*)pr;
      float4 e1 = *(const float4*)(pr + 4);
      float ev[8] = {e0.x, e0.y, e0.z, e0.w, e1.x, e1.y, e1.z, e1.w};
      bf16x8 ph, pm, pl;
#pragma unroll
      for (int jj = 0; jj < 8; ++jj) {
        const float e = ev[jj];
        const u16 hu = f2b(e);
        const float r1 = __fsub_rn(e, b2f(hu));
        const u16 mu = f2b(r1);
        const float r2 = __fsub_rn(r1, b2f(mu));
        const u16 lu = f2b(r2);
        ph[jj] = (short)hu;
        pm[jj] = (short)mu;
        pl[jj] = (short)lu;
      }
#pragma unroll
      for (int n = 0; n < 4; ++n) {
        const int dd = 16 * n + c;
        bf16x8 vv = *(const bf16x8*)&Vs[dd][((ks * 4 + g) ^ (c & 7)) << 3];
        oacc[n] = MFMA_BF16(ph, vv, oacc[n], 0, 0, 0);
        oacc[n] = MFMA_BF16(pm, vv, oacc[n], 0, 0, 0);
        oacc[n] = MFMA_BF16(pl, vv, oacc[n], 0, 0, 0);
      }
    }
  }
#pragma unroll
  for (int off = 1; off <= 8; off <<= 1)
#pragma unroll
    for (int reg = 0; reg < 4; ++reg) ls[reg] += __shfl_xor(ls[reg], off);

  float am = 0.f;
#pragma unroll
  for (int reg = 0; reg < 4; ++reg) {
    const float L = ls[reg] + 1e-6f;  // reference: /(sum + 1e-6)
    const size_t orow = ((size_t)(b * S_) + qbase + 4 * g + reg) * DM_ + h * 64;
#pragma unroll
    for (int n = 0; n < 4; ++n) {
      const float val = __fmul_rn(oacc[n][reg] / L, sv);
      ao[orow + n * 16 + c] = val;
      am = fmaxf(am, fabsf(val));
    }
  }
#pragma unroll
  for (int off = 1; off <= 32; off <<= 1) am = fmaxf(am, __shfl_xor(am, off));
  if (lane == 0) atomicMax(amax_out, __float_as_uint(am));
}

extern "C" void kernel_launch(void* const* d_in, const int* in_sizes, int n_in,
                              void* d_out, int out_size, void* d_ws, size_t ws_size,
                              hipStream_t stream) {
  const float* inputs_q  = (const float*)d_in[0];
  const float* inputs_kv = (const float*)d_in[1];
  const float* Wq = (const float*)d_in[2];
  const float* bq = (const float*)d_in[3];
  const float* Wk = (const float*)d_in[4];
  const float* bk = (const float*)d_in[5];
  const float* Wv = (const float*)d_in[6];
  const float* bv = (const float*)d_in[7];
  const float* Wo = (const float*)d_in[8];
  const float* bo = (const float*)d_in[9];
  const float* rel = (const float*)d_in[10];
  float* out = (float*)d_out;

  char* ws = (char*)d_ws;
  constexpr size_t MB = 1024 * 1024;
  // slots: 0 sx_q, 1 sx_kv, 2 sWq, 3 sWk, 4 sWv, 5 sWo, 6 sq, 7 sk, 8 sv, 9 sao
  unsigned* slots = (unsigned*)ws;
  u16* xq_b  = (u16*)(ws + 1024);
  u16* xkv_b = (u16*)((char*)xq_b + 8 * MB);
  u16* wq_b  = (u16*)((char*)xkv_b + 8 * MB);
  u16* wk_b  = (u16*)((char*)wq_b + 2 * MB);
  u16* wv_b  = (u16*)((char*)wk_b + 2 * MB);
  u16* wo_b  = (u16*)((char*)wv_b + 2 * MB);
  u16* q_b   = (u16*)((char*)wo_b + 2 * MB);
  u16* k_b   = (u16*)((char*)q_b + 8 * MB);
  u16* vT_b  = (u16*)((char*)k_b + 8 * MB);   // [b][h][d=64][kv=1024]
  u16* ao_b  = (u16*)((char*)vT_b + 8 * MB);
  float* tf  = (float*)((char*)ao_b + 8 * MB);  // 16 MB f32 scratch
  float* Mg  = (float*)((char*)tf + 16 * MB);   // 256 KB row-max scratch
  (void)ws_size; (void)in_sizes; (void)n_in; (void)out_size;

  const int n4_x = (B_ * S_ * DM_) / 4, n4_w = (DM_ * DM_) / 4;
  const int n8_x = (B_ * S_ * DM_) / 8;

  zero_slots_kernel<<<1, 64, 0, stream>>>(slots);

  Ptr6 a6;
  a6.p[0] = inputs_q;  a6.n4[0] = n4_x;
  a6.p[1] = inputs_kv; a6.n4[1] = n4_x;
  a6.p[2] = Wq; a6.n4[2] = n4_w;
  a6.p[3] = Wk; a6.n4[3] = n4_w;
  a6.p[4] = Wv; a6.n4[4] = n4_w;
  a6.p[5] = Wo; a6.n4[5] = n4_w;
  absmax6_kernel<<<dim3(128, 6), 256, 0, stream>>>(a6, slots);

  quantize2_kernel<<<dim3(512, 2), 256, 0, stream>>>(inputs_q, inputs_kv, xq_b, xkv_b,
                                                     slots, n8_x);
  W4 w4;
  w4.w[0] = Wq; w4.wt[0] = wq_b;
  w4.w[1] = Wk; w4.wt[1] = wk_b;
  w4.w[2] = Wv; w4.wt[2] = wv_b;
  w4.w[3] = Wo; w4.wt[3] = wo_b;
  quantW4_kernel<<<dim3(16, 16, 4), 256, 0, stream>>>(w4, slots);

  gemm128_kernel<<<512, 256, 0, stream>>>(xq_b, wq_b, slots + 0, slots + 2, bq, tf, slots + 6);
  quantize_bf16_kernel<<<1024, 256, 0, stream>>>(tf, n8_x, slots + 6, q_b);
  gemm128_kernel<<<512, 256, 0, stream>>>(xkv_b, wk_b, slots + 1, slots + 3, bk, tf, slots + 7);
  quantize_bf16_kernel<<<1024, 256, 0, stream>>>(tf, n8_x, slots + 7, k_b);
  gemm128_kernel<<<512, 256, 0, stream>>>(xkv_b, wv_b, slots + 1, slots + 4, bv, tf, slots + 8);
  quantizeT_v_kernel<<<dim3(64, 16), 256, 0, stream>>>(tf, slots + 8, vT_b);

  attn_max_kernel<<<1024, 256, 0, stream>>>(q_b, k_b, slots, rel, Mg);
  attn_av_kernel<<<1024, 256, 0, stream>>>(q_b, k_b, vT_b, slots, rel, Mg, tf, slots + 9);

  quantize_bf16_kernel<<<1024, 256, 0, stream>>>(tf, n8_x, slots + 9, ao_b);

  gemm128_kernel<<<512, 256, 0, stream>>>(ao_b, wo_b, slots + 9, slots + 5, bo, out, nullptr);
}

// Round 6
// 428.390 us; speedup vs baseline: 1.0338x; 1.0338x over previous
//
#include <hip/hip_runtime.h>
#include <hip/hip_bf16.h>
#include <stdint.h>

// B=4, Sq=Skv=1024, H=16, D=64, DM=1024, MRP=32
static constexpr int B_ = 4, S_ = 1024, H_ = 16, D_ = 64, DM_ = 1024;
// sqrt(64) * 1024^0.25 in fp32 exactly as np computes it
static constexpr float SF_ = 45.254833221435546875f;
static constexpr float RCP_SF_ = 1.0f / SF_;

typedef unsigned short u16;
typedef __attribute__((ext_vector_type(8))) short bf16x8;
typedef __attribute__((ext_vector_type(4))) float f32x4;

#define MFMA_BF16 __builtin_amdgcn_mfma_f32_16x16x32_bf16

typedef const __attribute__((address_space(1))) void CGV;
typedef __attribute__((address_space(3))) void LDSV;
__device__ __forceinline__ void gload16(const void* g, void* l) {
  __builtin_amdgcn_global_load_lds((CGV*)g, (LDSV*)l, 16, 0, 0);
}

__device__ __forceinline__ float slot_scale(const unsigned* s) {
  return __uint_as_float(*s) / 127.0f + 1e-8f;  // absmax/127 + 1e-8, reference order
}
__device__ __forceinline__ float quantf(float x, float s) {
  return fminf(fmaxf(rintf(x / s), -127.f), 127.f);  // RNE like jnp.round
}
__device__ __forceinline__ u16 f2b(float x) {  // float -> bf16 (HIP conversion)
  union { __hip_bfloat16 h; u16 u; } cv;
  cv.h = __float2bfloat16(x);
  return cv.u;
}
__device__ __forceinline__ float b2f(u16 u) { return __uint_as_float((unsigned)u << 16); }
__device__ __forceinline__ u16 qb16(float x, float s) { return f2b(quantf(x, s)); }
__device__ __forceinline__ float div_sf(float t2) {
  // correctly-rounded t2/SF_ (Markstein)
  float q0 = t2 * RCP_SF_;
  float r = fmaf(-SF_, q0, t2);
  return fmaf(r, RCP_SF_, q0);
}

__global__ void zero_slots_kernel(unsigned* slots) {
  if (threadIdx.x < 16) slots[threadIdx.x] = 0u;
}

struct Ptr6 { const float* p[6]; int n4[6]; };

__global__ __launch_bounds__(256) void absmax6_kernel(Ptr6 a, unsigned* __restrict__ slots) {
  const int y = blockIdx.y;
  const float4* x4 = (const float4*)a.p[y];
  const int n4 = a.n4[y];
  float m = 0.f;
  for (int i = blockIdx.x * 256 + threadIdx.x; i < n4; i += gridDim.x * 256) {
    float4 v = x4[i];
    m = fmaxf(m, fmaxf(fmaxf(fabsf(v.x), fabsf(v.y)), fmaxf(fabsf(v.z), fabsf(v.w))));
  }
#pragma unroll
  for (int off = 32; off; off >>= 1) m = fmaxf(m, __shfl_xor(m, off));
  if ((threadIdx.x & 63) == 0) atomicMax(slots + y, __float_as_uint(m));
}

__device__ __forceinline__ void quant_body(const float* __restrict__ x, int n8, float s,
                                           u16* __restrict__ out) {
  for (int i = blockIdx.x * 256 + threadIdx.x; i < n8; i += gridDim.x * 256) {
    float4 v0 = *((const float4*)x + 2 * (size_t)i);
    float4 v1 = *((const float4*)x + 2 * (size_t)i + 1);
    int4 o;
    o.x = (int)qb16(v0.x, s) | ((int)qb16(v0.y, s) << 16);
    o.y = (int)qb16(v0.z, s) | ((int)qb16(v0.w, s) << 16);
    o.z = (int)qb16(v1.x, s) | ((int)qb16(v1.y, s) << 16);
    o.w = (int)qb16(v1.z, s) | ((int)qb16(v1.w, s) << 16);
    *((int4*)out + i) = o;
  }
}

__global__ __launch_bounds__(256) void quantize_bf16_kernel(const float* __restrict__ x, int n8,
                                                            const unsigned* __restrict__ slot,
                                                            u16* __restrict__ out) {
  quant_body(x, n8, slot_scale(slot), out);
}

__global__ __launch_bounds__(256) void quantize2_kernel(const float* __restrict__ x0,
                                                        const float* __restrict__ x1,
                                                        u16* __restrict__ o0, u16* __restrict__ o1,
                                                        const unsigned* __restrict__ slots, int n8) {
  const int y = blockIdx.y;
  quant_body(y ? x1 : x0, n8, slot_scale(slots + y), y ? o1 : o0);
}

// Quantize [B*S][DM] f32 -> per-(b,h) CONTIGUOUS panel xp[(b*16+h)][s][64] (bf16-held ints).
// Contiguous panels keep L2 set-indexing uniform (the strided h-slice layout thrashed L2).
__global__ __launch_bounds__(256) void quantizeP_kernel(const float* __restrict__ xf,
                                                        const unsigned* __restrict__ slot,
                                                        u16* __restrict__ xp) {
  const float s = slot_scale(slot);
  const int st = blockIdx.x & 15, bh = blockIdx.x >> 4;
  const int b = bh >> 4, h = bh & 15;
  const int tid = threadIdx.x;
  const int r = tid >> 2, seg = (tid & 3) * 16;
  const float* src = &xf[((size_t)(b * S_) + st * 64 + r) * DM_ + h * 64 + seg];
  u16 qv[16];
#pragma unroll
  for (int i = 0; i < 16; i += 4) {
    float4 v = *(const float4*)(src + i);
    qv[i] = qb16(v.x, s); qv[i + 1] = qb16(v.y, s);
    qv[i + 2] = qb16(v.z, s); qv[i + 3] = qb16(v.w, s);
  }
  u16* dst = &xp[((size_t)bh * S_ + st * 64 + r) * 64 + seg];
  *(int4*)dst = *(const int4*)&qv[0];
  *(int4*)(dst + 8) = *(const int4*)&qv[8];
}

// Quantize v (float [B*S][DM]) and write TRANSPOSED per-(b,h): vT[((b*16+h)*64 + d)][kv]
__global__ __launch_bounds__(256) void quantizeT_v_kernel(const float* __restrict__ vf,
                                                          const unsigned* __restrict__ slot,
                                                          u16* __restrict__ vT) {
  __shared__ u16 t[64][72];
  const float s = slot_scale(slot);
  const int bt = blockIdx.x;           // b*16 + kvtile
  const int h = blockIdx.y;
  const int b = bt >> 4, kt = bt & 15;
  const int tid = threadIdx.x;
  const int row = tid >> 2, seg = (tid & 3) * 16;  // kv-local row, 16 d-cols
  const float* src = &vf[((size_t)(b * S_) + kt * 64 + row) * DM_ + h * 64 + seg];
  float4 v0 = *(const float4*)src;
  float4 v1 = *(const float4*)(src + 4);
  float4 v2 = *(const float4*)(src + 8);
  float4 v3 = *(const float4*)(src + 12);
  t[seg + 0][row] = qb16(v0.x, s);  t[seg + 1][row] = qb16(v0.y, s);
  t[seg + 2][row] = qb16(v0.z, s);  t[seg + 3][row] = qb16(v0.w, s);
  t[seg + 4][row] = qb16(v1.x, s);  t[seg + 5][row] = qb16(v1.y, s);
  t[seg + 6][row] = qb16(v1.z, s);  t[seg + 7][row] = qb16(v1.w, s);
  t[seg + 8][row] = qb16(v2.x, s);  t[seg + 9][row] = qb16(v2.y, s);
  t[seg + 10][row] = qb16(v2.z, s); t[seg + 11][row] = qb16(v2.w, s);
  t[seg + 12][row] = qb16(v3.x, s); t[seg + 13][row] = qb16(v3.y, s);
  t[seg + 14][row] = qb16(v3.z, s); t[seg + 15][row] = qb16(v3.w, s);
  __syncthreads();
  const int d = tid >> 2, s2 = (tid & 3) * 16;
  u16* dst = &vT[((size_t)(b * 16 + h) * 64 + d) * (size_t)S_ + kt * 64 + s2];
  *(int4*)dst = *(const int4*)&t[d][s2];
  *(int4*)(dst + 8) = *(const int4*)&t[d][s2 + 8];
}

// Quantize weight [K,N] -> transposed bf16 [N][K], 4 weights batched via z
struct W4 { const float* w[4]; u16* wt[4]; };
__global__ __launch_bounds__(256) void quantW4_kernel(W4 a, const unsigned* __restrict__ slots) {
  __shared__ u16 t[64][72];
  const int z = blockIdx.z;
  const float* w = a.w[z];
  u16* wt = a.wt[z];
  const float s = slot_scale(slots + 2 + z);
  const int k0 = blockIdx.y * 64, n0 = blockIdx.x * 64;
  const int tid = threadIdx.x;
#pragma unroll
  for (int rr = 0; rr < 4; rr++) {
    const int row = (tid >> 4) + rr * 16;  // k
    const int col = (tid & 15) * 4;        // n
    float4 v = *(const float4*)&w[(size_t)(k0 + row) * DM_ + n0 + col];
    t[col + 0][row] = qb16(v.x, s);
    t[col + 1][row] = qb16(v.y, s);
    t[col + 2][row] = qb16(v.z, s);
    t[col + 3][row] = qb16(v.w, s);
  }
  __syncthreads();
  const int nr = tid >> 2, kc = (tid & 3) * 16;
  *(int4*)&wt[(size_t)(n0 + nr) * DM_ + k0 + kc] = *(const int4*)&t[nr][kc];
  *(int4*)&wt[(size_t)(n0 + nr) * DM_ + k0 + kc + 8] = *(const int4*)&t[nr][kc + 8];
}

// C[M,N] = exact-int (A[M,K] . Bt[N,K]^T) * (sA*sB) + bias[N].  M=4096, N=K=1024.
__global__ __launch_bounds__(256) void gemm128_kernel(
    const u16* __restrict__ A, const u16* __restrict__ Bt,
    const unsigned* __restrict__ slotA, const unsigned* __restrict__ slotB,
    const float* __restrict__ bias, float* __restrict__ C,
    unsigned* __restrict__ amax_out) {
  __shared__ u16 As[2][128][64];
  __shared__ u16 Bs[2][64][64];
  const int N = DM_, K = DM_;
  const int id = blockIdx.x;                       // 0..511
  const int lin = (id & 7) * 64 + (id >> 3);       // XCD-contiguous m-panels
  const int by = lin >> 4, bx = lin & 15;
  const int m0 = by * 128, n0 = bx * 64;
  const int tid = threadIdx.x, w = tid >> 6, lane = tid & 63;
  const int c = lane & 15, g = lane >> 4;
  const int wr = w >> 1, wc = w & 1;
  const int lr = lane >> 3, lc = lane & 7;
  const int schunk = (lc ^ lr) << 3;

  f32x4 acc[4][2] = {};

  auto stage = [&](int buf, int kc) {
#pragma unroll
    for (int p = 0; p < 4; ++p) {
      const int r0 = w * 32 + p * 8;
      gload16(&A[(size_t)(m0 + r0 + lr) * K + kc + schunk], &As[buf][r0][0]);
    }
#pragma unroll
    for (int p = 0; p < 2; ++p) {
      const int r0 = w * 16 + p * 8;
      gload16(&Bt[(size_t)(n0 + r0 + lr) * K + kc + schunk], &Bs[buf][r0][0]);
    }
  };

  stage(0, 0);
  __syncthreads();
  for (int kt = 0; kt < 16; ++kt) {
    const int buf = kt & 1;
    if (kt < 15) stage(buf ^ 1, (kt + 1) * 64);
#pragma unroll
    for (int ks = 0; ks < 2; ++ks) {
      const int rswz = ((ks * 4 + g) ^ (c & 7)) << 3;
      bf16x8 b0 = *(const bf16x8*)&Bs[buf][wc * 32 + c][rswz];
      bf16x8 b1 = *(const bf16x8*)&Bs[buf][wc * 32 + 16 + c][rswz];
#pragma unroll
      for (int i = 0; i < 4; ++i) {
        bf16x8 av = *(const bf16x8*)&As[buf][wr * 64 + i * 16 + c][rswz];
        acc[i][0] = MFMA_BF16(av, b0, acc[i][0], 0, 0, 0);
        acc[i][1] = MFMA_BF16(av, b1, acc[i][1], 0, 0, 0);
      }
    }
    __syncthreads();
  }

  const float sAB = slot_scale(slotA) * slot_scale(slotB);
  float am = 0.f;
#pragma unroll
  for (int i = 0; i < 4; ++i)
#pragma unroll
    for (int j = 0; j < 2; ++j)
#pragma unroll
      for (int reg = 0; reg < 4; ++reg) {
        const int m = m0 + wr * 64 + i * 16 + 4 * g + reg;
        const int nn = n0 + wc * 32 + j * 16 + c;
        const float val = __fadd_rn(__fmul_rn(acc[i][j][reg], sAB), bias[nn]);
        C[(size_t)m * N + nn] = val;
        am = fmaxf(am, fabsf(val));
      }
  if (amax_out) {
#pragma unroll
    for (int off = 32; off; off >>= 1) am = fmaxf(am, __shfl_xor(am, off));
    if (lane == 0) atomicMax(amax_out, __float_as_uint(am));
  }
}

// Fused attention on CONTIGUOUS per-(b,h) panels: q_p/k_p [(bh)][s][64], vT [(bh)*64+d][kv].
// Two exact passes in one kernel (M kept in registers). Double-buffered global_load_lds
// staged one chunk ahead (overlaps with compute until the barrier drain).
__global__ __launch_bounds__(256, 3) void attn_kernel(
    const u16* __restrict__ qp_, const u16* __restrict__ kp_, const u16* __restrict__ vTb_,
    const unsigned* __restrict__ slots, const float* __restrict__ rel,
    float* __restrict__ ao, unsigned* __restrict__ amax_out) {
  __shared__ u16 Ks[2][64][64];
  __shared__ u16 Vs[2][64][64];
  __shared__ float Pf[4][16][68];
  __shared__ float biasT[68];

  const int id = blockIdx.x;        // XCD-grouped: 16 qt-blocks of one (b,h) per XCD
  const int rX = id & 7, jX = id >> 3;
  const int qt = jX & 15, gbh = (jX >> 4) * 8 + rX;
  const int h = gbh & 15, b = gbh >> 4;

  const int tid = threadIdx.x;
  const int w = tid >> 6, lane = tid & 63;
  const int c = lane & 15, g = lane >> 4;
  const int lr = lane >> 3, lc = lane & 7;
  const int schunk = (lc ^ lr) << 3;

  const float sqk = slot_scale(slots + 6) * slot_scale(slots + 7);
  const float sv = slot_scale(slots + 8);
  if (tid < 65) biasT[tid] = rel[tid * D_ + h];

  const int qbase = qt * 64 + w * 16;
  const size_t ppan = (size_t)gbh * S_ * 64;           // q/k panel base (u16)
  const size_t vpan = (size_t)gbh * 64 * (size_t)S_;   // vT panel base (u16)
  const size_t qrow = ppan + (size_t)(qbase + c) * 64;
  const bf16x8 qA0 = *(const bf16x8*)&qp_[qrow + g * 8];
  const bf16x8 qA1 = *(const bf16x8*)&qp_[qrow + 32 + g * 8];

  auto stageK = [&](int buf, int ch) {
#pragma unroll
    for (int p = 0; p < 2; ++p) {
      const int r0 = w * 16 + p * 8;
      gload16(&kp_[ppan + (size_t)(ch * 64 + r0 + lr) * 64 + schunk], &Ks[buf][r0][0]);
    }
  };
  auto stageV = [&](int buf, int ch) {
#pragma unroll
    for (int p = 0; p < 2; ++p) {
      const int r0 = w * 16 + p * 8;
      gload16(&vTb_[vpan + (size_t)(r0 + lr) * S_ + ch * 64 + schunk], &Vs[buf][r0][0]);
    }
  };

  // ---- pass 1: exact row max of pre-div scores ----
  float m2[4] = {-3.4e38f, -3.4e38f, -3.4e38f, -3.4e38f};
  stageK(0, 0);
  __syncthreads();
  const float b_lo = biasT[0], b_hi = biasT[64];
  for (int ch = 0; ch < 16; ++ch) {
    const int buf = ch & 1;
    if (ch < 15) stageK(buf ^ 1, ch + 1);
#pragma unroll
    for (int t = 0; t < 4; ++t) {
      f32x4 sacc = {0.f, 0.f, 0.f, 0.f};
      const int kr = t * 16 + c, sw = c & 7;
      bf16x8 k0 = *(const bf16x8*)&Ks[buf][kr][(g ^ sw) << 3];
      bf16x8 k1 = *(const bf16x8*)&Ks[buf][kr][((4 + g) ^ sw) << 3];
      sacc = MFMA_BF16(qA0, k0, sacc, 0, 0, 0);
      sacc = MFMA_BF16(qA1, k1, sacc, 0, 0, 0);
      const int kv0 = ch * 64 + t * 16;
      float bb[4];
      if (kv0 >= qbase + 47) {
        bb[0] = bb[1] = bb[2] = bb[3] = b_lo;
      } else if (qbase >= kv0 + 47) {
        bb[0] = bb[1] = bb[2] = bb[3] = b_hi;
      } else {
        const int jg = kv0 + c;
#pragma unroll
        for (int reg = 0; reg < 4; ++reg) {
          int dp = qbase + 4 * g + reg - jg + 32;
          dp = dp < 0 ? 0 : (dp > 64 ? 64 : dp);
          bb[reg] = biasT[dp];
        }
      }
#pragma unroll
      for (int reg = 0; reg < 4; ++reg)
        m2[reg] = fmaxf(m2[reg], __fadd_rn(__fmul_rn(sacc[reg], sqk), bb[reg]));
    }
    __syncthreads();
  }
#pragma unroll
  for (int off = 1; off <= 8; off <<= 1)
#pragma unroll
    for (int reg = 0; reg < 4; ++reg) m2[reg] = fmaxf(m2[reg], __shfl_xor(m2[reg], off));
  float M[4];
#pragma unroll
  for (int reg = 0; reg < 4; ++reg) M[reg] = div_sf(m2[reg]);  // monotone => exact

  // ---- pass 2: exp (hw), 3-way bf16 split, PV MFMA ----
  f32x4 oacc[4] = {};
  float ls[4] = {0.f, 0.f, 0.f, 0.f};
  stageK(0, 0);
  stageV(0, 0);
  __syncthreads();
  for (int ch = 0; ch < 16; ++ch) {
    const int buf = ch & 1;
    if (ch < 15) {
      stageK(buf ^ 1, ch + 1);
      stageV(buf ^ 1, ch + 1);
    }
#pragma unroll
    for (int t = 0; t < 4; ++t) {
      f32x4 sacc = {0.f, 0.f, 0.f, 0.f};
      const int kr = t * 16 + c, sw = c & 7;
      bf16x8 k0 = *(const bf16x8*)&Ks[buf][kr][(g ^ sw) << 3];
      bf16x8 k1 = *(const bf16x8*)&Ks[buf][kr][((4 + g) ^ sw) << 3];
      sacc = MFMA_BF16(qA0, k0, sacc, 0, 0, 0);
      sacc = MFMA_BF16(qA1, k1, sacc, 0, 0, 0);
      const int kv0 = ch * 64 + t * 16;
      float bb[4];
      if (kv0 >= qbase + 47) {
        bb[0] = bb[1] = bb[2] = bb[3] = b_lo;
      } else if (qbase >= kv0 + 47) {
        bb[0] = bb[1] = bb[2] = bb[3] = b_hi;
      } else {
        const int jg = kv0 + c;
#pragma unroll
        for (int reg = 0; reg < 4; ++reg) {
          int dp = qbase + 4 * g + reg - jg + 32;
          dp = dp < 0 ? 0 : (dp > 64 ? 64 : dp);
          bb[reg] = biasT[dp];
        }
      }
      float* pw = &Pf[w][4 * g][t * 16 + c];
#pragma unroll
      for (int reg = 0; reg < 4; ++reg) {
        const float sc = div_sf(__fadd_rn(__fmul_rn(sacc[reg], sqk), bb[reg]));
        const float e = __expf(sc - M[reg]);   // hw v_exp_f32
        ls[reg] += e;
        pw[reg * 68] = e;
      }
    }
    // PV: read own wave's P rows (wave-local, no barrier), 3-way bf16 split, MFMA vs Vs
#pragma unroll
    for (int ks = 0; ks < 2; ++ks) {
      const float* pr = &Pf[w][c][ks * 32 + g * 8];
      float4 e0 = *(const float4*)pr;
      float4 e1 = *(const float4*)(pr + 4);
      float ev[8] = {e0.x, e0.y, e0.z, e0.w, e1.x, e1.y, e1.z, e1.w};
      bf16x8 ph, pm, pl;
#pragma unroll
      for (int jj = 0; jj < 8; ++jj) {
        const float e = ev[jj];
        const u16 hu = f2b(e);
        const float r1 = __fsub_rn(e, b2f(hu));
        const u16 mu = f2b(r1);
        const float r2 = __fsub_rn(r1, b2f(mu));
        const u16 lu = f2b(r2);
        ph[jj] = (short)hu;
        pm[jj] = (short)mu;
        pl[jj] = (short)lu;
      }
#pragma unroll
      for (int n = 0; n < 4; ++n) {
        const int dd = 16 * n + c;
        bf16x8 vv = *(const bf16x8*)&Vs[buf][dd][((ks * 4 + g) ^ (c & 7)) << 3];
        oacc[n] = MFMA_BF16(ph, vv, oacc[n], 0, 0, 0);
        oacc[n] = MFMA_BF16(pm, vv, oacc[n], 0, 0, 0);
        oacc[n] = MFMA_BF16(pl, vv, oacc[n], 0, 0, 0);
      }
    }
    __syncthreads();
  }
#pragma unroll
  for (int off = 1; off <= 8; off <<= 1)
#pragma unroll
    for (int reg = 0; reg < 4; ++reg) ls[reg] += __shfl_xor(ls[reg], off);

  float am = 0.f;
#pragma unroll
  for (int reg = 0; reg < 4; ++reg) {
    const float L = ls[reg] + 1e-6f;  // reference: /(sum + 1e-6)
    const size_t orow = ((size_t)(b * S_) + qbase + 4 * g + reg) * DM_ + h * 64;
#pragma unroll
    for (int n = 0; n < 4; ++n) {
      const float val = __fmul_rn(oacc[n][reg] / L, sv);
      ao[orow + n * 16 + c] = val;
      am = fmaxf(am, fabsf(val));
    }
  }
#pragma unroll
  for (int off = 1; off <= 32; off <<= 1) am = fmaxf(am, __shfl_xor(am, off));
  if (lane == 0) atomicMax(amax_out, __float_as_uint(am));
}

extern "C" void kernel_launch(void* const* d_in, const int* in_sizes, int n_in,
                              void* d_out, int out_size, void* d_ws, size_t ws_size,
                              hipStream_t stream) {
  const float* inputs_q  = (const float*)d_in[0];
  const float* inputs_kv = (const float*)d_in[1];
  const float* Wq = (const float*)d_in[2];
  const float* bq = (const float*)d_in[3];
  const float* Wk = (const float*)d_in[4];
  const float* bk = (const float*)d_in[5];
  const float* Wv = (const float*)d_in[6];
  const float* bv = (const float*)d_in[7];
  const float* Wo = (const float*)d_in[8];
  const float* bo = (const float*)d_in[9];
  const float* rel = (const float*)d_in[10];
  float* out = (float*)d_out;

  char* ws = (char*)d_ws;
  constexpr size_t MB = 1024 * 1024;
  // slots: 0 sx_q, 1 sx_kv, 2 sWq, 3 sWk, 4 sWv, 5 sWo, 6 sq, 7 sk, 8 sv, 9 sao
  unsigned* slots = (unsigned*)ws;
  u16* xq_b  = (u16*)(ws + 1024);
  u16* xkv_b = (u16*)((char*)xq_b + 8 * MB);
  u16* wq_b  = (u16*)((char*)xkv_b + 8 * MB);
  u16* wk_b  = (u16*)((char*)wq_b + 2 * MB);
  u16* wv_b  = (u16*)((char*)wk_b + 2 * MB);
  u16* wo_b  = (u16*)((char*)wv_b + 2 * MB);
  u16* q_p   = (u16*)((char*)wo_b + 2 * MB);  // [bh][s][64] contiguous panels
  u16* k_p   = (u16*)((char*)q_p + 8 * MB);   // [bh][s][64]
  u16* vT_b  = (u16*)((char*)k_p + 8 * MB);   // [bh*64+d][kv]
  u16* ao_b  = (u16*)((char*)vT_b + 8 * MB);
  float* tf  = (float*)((char*)ao_b + 8 * MB);  // 16 MB f32 scratch
  (void)ws_size; (void)in_sizes; (void)n_in; (void)out_size;

  const int n4_x = (B_ * S_ * DM_) / 4, n4_w = (DM_ * DM_) / 4;
  const int n8_x = (B_ * S_ * DM_) / 8;

  zero_slots_kernel<<<1, 64, 0, stream>>>(slots);

  Ptr6 a6;
  a6.p[0] = inputs_q;  a6.n4[0] = n4_x;
  a6.p[1] = inputs_kv; a6.n4[1] = n4_x;
  a6.p[2] = Wq; a6.n4[2] = n4_w;
  a6.p[3] = Wk; a6.n4[3] = n4_w;
  a6.p[4] = Wv; a6.n4[4] = n4_w;
  a6.p[5] = Wo; a6.n4[5] = n4_w;
  absmax6_kernel<<<dim3(128, 6), 256, 0, stream>>>(a6, slots);

  quantize2_kernel<<<dim3(512, 2), 256, 0, stream>>>(inputs_q, inputs_kv, xq_b, xkv_b,
                                                     slots, n8_x);
  W4 w4;
  w4.w[0] = Wq; w4.wt[0] = wq_b;
  w4.w[1] = Wk; w4.wt[1] = wk_b;
  w4.w[2] = Wv; w4.wt[2] = wv_b;
  w4.w[3] = Wo; w4.wt[3] = wo_b;
  quantW4_kernel<<<dim3(16, 16, 4), 256, 0, stream>>>(w4, slots);

  gemm128_kernel<<<512, 256, 0, stream>>>(xq_b, wq_b, slots + 0, slots + 2, bq, tf, slots + 6);
  quantizeP_kernel<<<1024, 256, 0, stream>>>(tf, slots + 6, q_p);
  gemm128_kernel<<<512, 256, 0, stream>>>(xkv_b, wk_b, slots + 1, slots + 3, bk, tf, slots + 7);
  quantizeP_kernel<<<1024, 256, 0, stream>>>(tf, slots + 7, k_p);
  gemm128_kernel<<<512, 256, 0, stream>>>(xkv_b, wv_b, slots + 1, slots + 4, bv, tf, slots + 8);
  quantizeT_v_kernel<<<dim3(64, 16), 256, 0, stream>>>(tf, slots + 8, vT_b);

  attn_kernel<<<1024, 256, 0, stream>>>(q_p, k_p, vT_b, slots, rel, tf, slots + 9);

  quantize_bf16_kernel<<<1024, 256, 0, stream>>>(tf, n8_x, slots + 9, ao_b);

  gemm128_kernel<<<512, 256, 0, stream>>>(ao_b, wo_b, slots + 9, slots + 5, bo, out, nullptr);
}

// Round 7
// 338.608 us; speedup vs baseline: 1.3078x; 1.2652x over previous
//
#include <hip/hip_runtime.h>
#include <hip/hip_bf16.h>
#include <stdint.h>

// B=4, Sq=Skv=1024, H=16, D=64, DM=1024, MRP=32
static constexpr int B_ = 4, S_ = 1024, H_ = 16, D_ = 64, DM_ = 1024;
// sqrt(64) * 1024^0.25 in fp32 exactly as np computes it
static constexpr float SF_ = 45.254833221435546875f;
static constexpr float RCP_SF_ = 1.0f / SF_;

typedef unsigned short u16;
typedef __attribute__((ext_vector_type(8))) short bf16x8;
typedef __attribute__((ext_vector_type(4))) float f32x4;

#define MFMA_BF16 __builtin_amdgcn_mfma_f32_16x16x32_bf16

typedef const __attribute__((address_space(1))) void CGV;
typedef __attribute__((address_space(3))) void LDSV;
__device__ __forceinline__ void gload16(const void* g, void* l) {
  __builtin_amdgcn_global_load_lds((CGV*)g, (LDSV*)l, 16, 0, 0);
}

__device__ __forceinline__ float slot_scale(const unsigned* s) {
  return __uint_as_float(*s) / 127.0f + 1e-8f;  // absmax/127 + 1e-8, reference order
}
__device__ __forceinline__ float quantf(float x, float s) {
  return fminf(fmaxf(rintf(x / s), -127.f), 127.f);  // RNE like jnp.round
}
__device__ __forceinline__ u16 f2b(float x) {  // float -> bf16 (HIP conversion)
  union { __hip_bfloat16 h; u16 u; } cv;
  cv.h = __float2bfloat16(x);
  return cv.u;
}
__device__ __forceinline__ float b2f(u16 u) { return __uint_as_float((unsigned)u << 16); }
__device__ __forceinline__ u16 qb16(float x, float s) { return f2b(quantf(x, s)); }
__device__ __forceinline__ float div_sf(float t2) {
  // correctly-rounded t2/SF_ (Markstein)
  float q0 = t2 * RCP_SF_;
  float r = fmaf(-SF_, q0, t2);
  return fmaf(r, RCP_SF_, q0);
}

__global__ void zero_slots_kernel(unsigned* slots) {
  if (threadIdx.x < 16) slots[threadIdx.x] = 0u;
}

struct Ptr6 { const float* p[6]; int n4[6]; };

__global__ __launch_bounds__(256) void absmax6_kernel(Ptr6 a, unsigned* __restrict__ slots) {
  const int y = blockIdx.y;
  const float4* x4 = (const float4*)a.p[y];
  const int n4 = a.n4[y];
  float m = 0.f;
  for (int i = blockIdx.x * 256 + threadIdx.x; i < n4; i += gridDim.x * 256) {
    float4 v = x4[i];
    m = fmaxf(m, fmaxf(fmaxf(fabsf(v.x), fabsf(v.y)), fmaxf(fabsf(v.z), fabsf(v.w))));
  }
#pragma unroll
  for (int off = 32; off; off >>= 1) m = fmaxf(m, __shfl_xor(m, off));
  if ((threadIdx.x & 63) == 0) atomicMax(slots + y, __float_as_uint(m));
}

__device__ __forceinline__ void quant_body(const float* __restrict__ x, int n8, float s,
                                           u16* __restrict__ out) {
  for (int i = blockIdx.x * 256 + threadIdx.x; i < n8; i += gridDim.x * 256) {
    float4 v0 = *((const float4*)x + 2 * (size_t)i);
    float4 v1 = *((const float4*)x + 2 * (size_t)i + 1);
    int4 o;
    o.x = (int)qb16(v0.x, s) | ((int)qb16(v0.y, s) << 16);
    o.y = (int)qb16(v0.z, s) | ((int)qb16(v0.w, s) << 16);
    o.z = (int)qb16(v1.x, s) | ((int)qb16(v1.y, s) << 16);
    o.w = (int)qb16(v1.z, s) | ((int)qb16(v1.w, s) << 16);
    *((int4*)out + i) = o;
  }
}

__global__ __launch_bounds__(256) void quantize_bf16_kernel(const float* __restrict__ x, int n8,
                                                            const unsigned* __restrict__ slot,
                                                            u16* __restrict__ out) {
  quant_body(x, n8, slot_scale(slot), out);
}

__global__ __launch_bounds__(256) void quantize2_kernel(const float* __restrict__ x0,
                                                        const float* __restrict__ x1,
                                                        u16* __restrict__ o0, u16* __restrict__ o1,
                                                        const unsigned* __restrict__ slots, int n8) {
  const int y = blockIdx.y;
  quant_body(y ? x1 : x0, n8, slot_scale(slots + y), y ? o1 : o0);
}

// Quantize [B*S][DM] f32 -> per-(b,h) CONTIGUOUS panel xp[(b*16+h)][s][64]
__global__ __launch_bounds__(256) void quantizeP_kernel(const float* __restrict__ xf,
                                                        const unsigned* __restrict__ slot,
                                                        u16* __restrict__ xp) {
  const float s = slot_scale(slot);
  const int st = blockIdx.x & 15, bh = blockIdx.x >> 4;
  const int b = bh >> 4, h = bh & 15;
  const int tid = threadIdx.x;
  const int r = tid >> 2, seg = (tid & 3) * 16;
  const float* src = &xf[((size_t)(b * S_) + st * 64 + r) * DM_ + h * 64 + seg];
  u16 qv[16];
#pragma unroll
  for (int i = 0; i < 16; i += 4) {
    float4 v = *(const float4*)(src + i);
    qv[i] = qb16(v.x, s); qv[i + 1] = qb16(v.y, s);
    qv[i + 2] = qb16(v.z, s); qv[i + 3] = qb16(v.w, s);
  }
  u16* dst = &xp[((size_t)bh * S_ + st * 64 + r) * 64 + seg];
  *(int4*)dst = *(const int4*)&qv[0];
  *(int4*)(dst + 8) = *(const int4*)&qv[8];
}

// Quantize v (float [B*S][DM]) -> TRANSPOSED per-(b,h): vT[((b*16+h)*64 + d)][kv]
__global__ __launch_bounds__(256) void quantizeT_v_kernel(const float* __restrict__ vf,
                                                          const unsigned* __restrict__ slot,
                                                          u16* __restrict__ vT) {
  __shared__ u16 t[64][72];
  const float s = slot_scale(slot);
  const int bt = blockIdx.x;           // b*16 + kvtile
  const int h = blockIdx.y;
  const int b = bt >> 4, kt = bt & 15;
  const int tid = threadIdx.x;
  const int row = tid >> 2, seg = (tid & 3) * 16;  // kv-local row, 16 d-cols
  const float* src = &vf[((size_t)(b * S_) + kt * 64 + row) * DM_ + h * 64 + seg];
  float4 v0 = *(const float4*)src;
  float4 v1 = *(const float4*)(src + 4);
  float4 v2 = *(const float4*)(src + 8);
  float4 v3 = *(const float4*)(src + 12);
  t[seg + 0][row] = qb16(v0.x, s);  t[seg + 1][row] = qb16(v0.y, s);
  t[seg + 2][row] = qb16(v0.z, s);  t[seg + 3][row] = qb16(v0.w, s);
  t[seg + 4][row] = qb16(v1.x, s);  t[seg + 5][row] = qb16(v1.y, s);
  t[seg + 6][row] = qb16(v1.z, s);  t[seg + 7][row] = qb16(v1.w, s);
  t[seg + 8][row] = qb16(v2.x, s);  t[seg + 9][row] = qb16(v2.y, s);
  t[seg + 10][row] = qb16(v2.z, s); t[seg + 11][row] = qb16(v2.w, s);
  t[seg + 12][row] = qb16(v3.x, s); t[seg + 13][row] = qb16(v3.y, s);
  t[seg + 14][row] = qb16(v3.z, s); t[seg + 15][row] = qb16(v3.w, s);
  __syncthreads();
  const int d = tid >> 2, s2 = (tid & 3) * 16;
  u16* dst = &vT[((size_t)(b * 16 + h) * 64 + d) * (size_t)S_ + kt * 64 + s2];
  *(int4*)dst = *(const int4*)&t[d][s2];
  *(int4*)(dst + 8) = *(const int4*)&t[d][s2 + 8];
}

// Quantize weight [K,N] -> transposed bf16 [N][K], 4 weights batched via z
struct W4 { const float* w[4]; u16* wt[4]; };
__global__ __launch_bounds__(256) void quantW4_kernel(W4 a, const unsigned* __restrict__ slots) {
  __shared__ u16 t[64][72];
  const int z = blockIdx.z;
  const float* w = a.w[z];
  u16* wt = a.wt[z];
  const float s = slot_scale(slots + 2 + z);
  const int k0 = blockIdx.y * 64, n0 = blockIdx.x * 64;
  const int tid = threadIdx.x;
#pragma unroll
  for (int rr = 0; rr < 4; rr++) {
    const int row = (tid >> 4) + rr * 16;  // k
    const int col = (tid & 15) * 4;        // n
    float4 v = *(const float4*)&w[(size_t)(k0 + row) * DM_ + n0 + col];
    t[col + 0][row] = qb16(v.x, s);
    t[col + 1][row] = qb16(v.y, s);
    t[col + 2][row] = qb16(v.z, s);
    t[col + 3][row] = qb16(v.w, s);
  }
  __syncthreads();
  const int nr = tid >> 2, kc = (tid & 3) * 16;
  *(int4*)&wt[(size_t)(n0 + nr) * DM_ + k0 + kc] = *(const int4*)&t[nr][kc];
  *(int4*)&wt[(size_t)(n0 + nr) * DM_ + k0 + kc + 8] = *(const int4*)&t[nr][kc + 8];
}

// C[M,N] = exact-int (A[M,K] . Bt[N,K]^T) * (sA*sB) + bias[N].  M=4096, N=K=1024.
__global__ __launch_bounds__(256) void gemm128_kernel(
    const u16* __restrict__ A, const u16* __restrict__ Bt,
    const unsigned* __restrict__ slotA, const unsigned* __restrict__ slotB,
    const float* __restrict__ bias, float* __restrict__ C,
    unsigned* __restrict__ amax_out) {
  __shared__ u16 As[2][128][64];
  __shared__ u16 Bs[2][64][64];
  const int N = DM_, K = DM_;
  const int id = blockIdx.x;                       // 0..511
  const int lin = (id & 7) * 64 + (id >> 3);       // XCD-contiguous m-panels
  const int by = lin >> 4, bx = lin & 15;
  const int m0 = by * 128, n0 = bx * 64;
  const int tid = threadIdx.x, w = tid >> 6, lane = tid & 63;
  const int c = lane & 15, g = lane >> 4;
  const int wr = w >> 1, wc = w & 1;
  const int lr = lane >> 3, lc = lane & 7;
  const int schunk = (lc ^ lr) << 3;

  f32x4 acc[4][2] = {};

  auto stage = [&](int buf, int kc) {
#pragma unroll
    for (int p = 0; p < 4; ++p) {
      const int r0 = w * 32 + p * 8;
      gload16(&A[(size_t)(m0 + r0 + lr) * K + kc + schunk], &As[buf][r0][0]);
    }
#pragma unroll
    for (int p = 0; p < 2; ++p) {
      const int r0 = w * 16 + p * 8;
      gload16(&Bt[(size_t)(n0 + r0 + lr) * K + kc + schunk], &Bs[buf][r0][0]);
    }
  };

  stage(0, 0);
  __syncthreads();
  for (int kt = 0; kt < 16; ++kt) {
    const int buf = kt & 1;
    if (kt < 15) stage(buf ^ 1, (kt + 1) * 64);
#pragma unroll
    for (int ks = 0; ks < 2; ++ks) {
      const int rswz = ((ks * 4 + g) ^ (c & 7)) << 3;
      bf16x8 b0 = *(const bf16x8*)&Bs[buf][wc * 32 + c][rswz];
      bf16x8 b1 = *(const bf16x8*)&Bs[buf][wc * 32 + 16 + c][rswz];
#pragma unroll
      for (int i = 0; i < 4; ++i) {
        bf16x8 av = *(const bf16x8*)&As[buf][wr * 64 + i * 16 + c][rswz];
        acc[i][0] = MFMA_BF16(av, b0, acc[i][0], 0, 0, 0);
        acc[i][1] = MFMA_BF16(av, b1, acc[i][1], 0, 0, 0);
      }
    }
    __syncthreads();
  }

  const float sAB = slot_scale(slotA) * slot_scale(slotB);
  float am = 0.f;
#pragma unroll
  for (int i = 0; i < 4; ++i)
#pragma unroll
    for (int j = 0; j < 2; ++j)
#pragma unroll
      for (int reg = 0; reg < 4; ++reg) {
        const int m = m0 + wr * 64 + i * 16 + 4 * g + reg;
        const int nn = n0 + wc * 32 + j * 16 + c;
        const float val = __fadd_rn(__fmul_rn(acc[i][j][reg], sAB), bias[nn]);
        C[(size_t)m * N + nn] = val;
        am = fmaxf(am, fabsf(val));
      }
  if (amax_out) {
#pragma unroll
    for (int off = 32; off; off >>= 1) am = fmaxf(am, __shfl_xor(am, off));
    if (lane == 0) atomicMax(amax_out, __float_as_uint(am));
  }
}

// Fused attention: 512 blocks; each handles TWO 64-row q-tiles (128 rows) of one (b,h).
// K/V register-staged into single-buffer LDS (clean HBM counters; no gload_lds phantom),
// loads issued before compute (async-split), ds_write after the post-compute barrier.
// Co-XCD grouping: XCD = id&7 owns bh in [8*XCD, 8*XCD+8) -> 2MB KV + 1MB Q fits L2.
__global__ __launch_bounds__(256) void attn_kernel(
    const u16* __restrict__ qp_, const u16* __restrict__ kp_, const u16* __restrict__ vTb_,
    const unsigned* __restrict__ slots, const float* __restrict__ rel,
    float* __restrict__ ao, unsigned* __restrict__ amax_out) {
  __shared__ u16 Ks[64][64];
  __shared__ u16 Vs[64][64];
  __shared__ float Pf[4][16][68];
  __shared__ float biasT[68];

  const int id = blockIdx.x;            // 512 blocks
  const int rX = id & 7, rest = id >> 3;
  const int qoct = rest & 7, bhi = rest >> 3;
  const int gbh = rX * 8 + bhi;         // co-XCD blocks share 8 bh panels
  const int h = gbh & 15, b = gbh >> 4;

  const int tid = threadIdx.x;
  const int w = tid >> 6, lane = tid & 63;
  const int c = lane & 15, g = lane >> 4;
  const int lr = lane >> 3, lc = lane & 7;
  const int schunk = (lc ^ lr) << 3;    // source-side XOR swizzle (16B chunks)

  const float sqk = slot_scale(slots + 6) * slot_scale(slots + 7);
  const float sv = slot_scale(slots + 8);
  if (tid < 65) biasT[tid] = rel[tid * D_ + h];

  const size_t ppan = (size_t)gbh * S_ * 64;           // q/k panel base (u16)
  const size_t vpan = (size_t)gbh * 64 * (size_t)S_;   // vT panel base (u16)

  const int qb2[2] = {qoct * 128 + w * 16, qoct * 128 + 64 + w * 16};
  bf16x8 qA0[2], qA1[2];
#pragma unroll
  for (int u = 0; u < 2; ++u) {
    const size_t qrow = ppan + (size_t)(qb2[u] + c) * 64;
    qA0[u] = *(const bf16x8*)&qp_[qrow + g * 8];
    qA1[u] = *(const bf16x8*)&qp_[qrow + 32 + g * 8];
  }

  int4 kreg[2], vreg[2];
  auto loadK = [&](int ch) {
#pragma unroll
    for (int p = 0; p < 2; ++p)
      kreg[p] = *(const int4*)&kp_[ppan + (size_t)(ch * 64 + w * 16 + p * 8 + lr) * 64 + schunk];
  };
  auto writeK = [&]() {
#pragma unroll
    for (int p = 0; p < 2; ++p)
      *(int4*)&Ks[w * 16 + p * 8 + lr][lc * 8] = kreg[p];
  };
  auto loadV = [&](int ch) {
#pragma unroll
    for (int p = 0; p < 2; ++p)
      vreg[p] = *(const int4*)&vTb_[vpan + (size_t)(w * 16 + p * 8 + lr) * S_ + ch * 64 + schunk];
  };
  auto writeV = [&]() {
#pragma unroll
    for (int p = 0; p < 2; ++p)
      *(int4*)&Vs[w * 16 + p * 8 + lr][lc * 8] = vreg[p];
  };

  // ---- pass 1: exact row max of pre-div scores ----
  float m2[2][4];
#pragma unroll
  for (int u = 0; u < 2; ++u)
#pragma unroll
    for (int reg = 0; reg < 4; ++reg) m2[u][reg] = -3.4e38f;

  loadK(0);
  writeK();
  __syncthreads();
  const float b_lo = biasT[0], b_hi = biasT[64];
  for (int ch = 0; ch < 16; ++ch) {
    if (ch < 15) loadK(ch + 1);       // issue next loads; latency hides under compute
#pragma unroll
    for (int u = 0; u < 2; ++u) {
      const int qbase = qb2[u];
#pragma unroll
      for (int t = 0; t < 4; ++t) {
        f32x4 sacc = {0.f, 0.f, 0.f, 0.f};
        const int kr = t * 16 + c, sw = c & 7;
        bf16x8 k0 = *(const bf16x8*)&Ks[kr][(g ^ sw) << 3];
        bf16x8 k1 = *(const bf16x8*)&Ks[kr][((4 + g) ^ sw) << 3];
        sacc = MFMA_BF16(qA0[u], k0, sacc, 0, 0, 0);
        sacc = MFMA_BF16(qA1[u], k1, sacc, 0, 0, 0);
        const int kv0 = ch * 64 + t * 16;
        float bb[4];
        if (kv0 >= qbase + 47) {
          bb[0] = bb[1] = bb[2] = bb[3] = b_lo;
        } else if (qbase >= kv0 + 47) {
          bb[0] = bb[1] = bb[2] = bb[3] = b_hi;
        } else {
          const int jg = kv0 + c;
#pragma unroll
          for (int reg = 0; reg < 4; ++reg) {
            int dp = qbase + 4 * g + reg - jg + 32;
            dp = dp < 0 ? 0 : (dp > 64 ? 64 : dp);
            bb[reg] = biasT[dp];
          }
        }
#pragma unroll
        for (int reg = 0; reg < 4; ++reg)
          m2[u][reg] = fmaxf(m2[u][reg], __fadd_rn(__fmul_rn(sacc[reg], sqk), bb[reg]));
      }
    }
    __syncthreads();                  // all waves done reading Ks
    if (ch < 15) { writeK(); __syncthreads(); }
  }
  float M[2][4];
#pragma unroll
  for (int u = 0; u < 2; ++u) {
#pragma unroll
    for (int off = 1; off <= 8; off <<= 1)
#pragma unroll
      for (int reg = 0; reg < 4; ++reg)
        m2[u][reg] = fmaxf(m2[u][reg], __shfl_xor(m2[u][reg], off));
#pragma unroll
    for (int reg = 0; reg < 4; ++reg) M[u][reg] = div_sf(m2[u][reg]);  // monotone => exact
  }

  // ---- pass 2: exp (hw), 3-way bf16 split, PV MFMA ----
  f32x4 oacc[2][4] = {};
  float ls[2][4] = {};
  loadK(0);
  loadV(0);
  writeK();
  writeV();
  __syncthreads();
  for (int ch = 0; ch < 16; ++ch) {
    if (ch < 15) { loadK(ch + 1); loadV(ch + 1); }
#pragma unroll
    for (int u = 0; u < 2; ++u) {
      const int qbase = qb2[u];
#pragma unroll
      for (int t = 0; t < 4; ++t) {
        f32x4 sacc = {0.f, 0.f, 0.f, 0.f};
        const int kr = t * 16 + c, sw = c & 7;
        bf16x8 k0 = *(const bf16x8*)&Ks[kr][(g ^ sw) << 3];
        bf16x8 k1 = *(const bf16x8*)&Ks[kr][((4 + g) ^ sw) << 3];
        sacc = MFMA_BF16(qA0[u], k0, sacc, 0, 0, 0);
        sacc = MFMA_BF16(qA1[u], k1, sacc, 0, 0, 0);
        const int kv0 = ch * 64 + t * 16;
        float bb[4];
        if (kv0 >= qbase + 47) {
          bb[0] = bb[1] = bb[2] = bb[3] = b_lo;
        } else if (qbase >= kv0 + 47) {
          bb[0] = bb[1] = bb[2] = bb[3] = b_hi;
        } else {
          const int jg = kv0 + c;
#pragma unroll
          for (int reg = 0; reg < 4; ++reg) {
            int dp = qbase + 4 * g + reg - jg + 32;
            dp = dp < 0 ? 0 : (dp > 64 ? 64 : dp);
            bb[reg] = biasT[dp];
          }
        }
        float* pw = &Pf[w][4 * g][t * 16 + c];
#pragma unroll
        for (int reg = 0; reg < 4; ++reg) {
          const float sc = div_sf(__fadd_rn(__fmul_rn(sacc[reg], sqk), bb[reg]));
          const float e = __expf(sc - M[u][reg]);   // hw v_exp_f32
          ls[u][reg] += e;
          pw[reg * 68] = e;
        }
      }
      // PV for this q-tile (Pf is wave-local: write->read ordered by lgkmcnt)
#pragma unroll
      for (int ks = 0; ks < 2; ++ks) {
        const float* pr = &Pf[w][c][ks * 32 + g * 8];
        float4 e0 = *(const float4*)pr;
        float4 e1 = *(const float4*)(pr + 4);
        float ev[8] = {e0.x, e0.y, e0.z, e0.w, e1.x, e1.y, e1.z, e1.w};
        bf16x8 ph, pm, pl;
#pragma unroll
        for (int jj = 0; jj < 8; ++jj) {
          const float e = ev[jj];
          const u16 hu = f2b(e);
          const float r1 = __fsub_rn(e, b2f(hu));
          const u16 mu = f2b(r1);
          const float r2 = __fsub_rn(r1, b2f(mu));
          const u16 lu = f2b(r2);
          ph[jj] = (short)hu;
          pm[jj] = (short)mu;
          pl[jj] = (short)lu;
        }
#pragma unroll
        for (int n = 0; n < 4; ++n) {
          const int dd = 16 * n + c;
          bf16x8 vv = *(const bf16x8*)&Vs[dd][((ks * 4 + g) ^ (c & 7)) << 3];
          oacc[u][n] = MFMA_BF16(ph, vv, oacc[u][n], 0, 0, 0);
          oacc[u][n] = MFMA_BF16(pm, vv, oacc[u][n], 0, 0, 0);
          oacc[u][n] = MFMA_BF16(pl, vv, oacc[u][n], 0, 0, 0);
        }
      }
    }
    __syncthreads();                  // all waves done reading Ks/Vs
    if (ch < 15) { writeK(); writeV(); __syncthreads(); }
  }

  float am = 0.f;
#pragma unroll
  for (int u = 0; u < 2; ++u) {
#pragma unroll
    for (int off = 1; off <= 8; off <<= 1)
#pragma unroll
      for (int reg = 0; reg < 4; ++reg) ls[u][reg] += __shfl_xor(ls[u][reg], off);
#pragma unroll
    for (int reg = 0; reg < 4; ++reg) {
      const float L = ls[u][reg] + 1e-6f;  // reference: /(sum + 1e-6)
      const size_t orow = ((size_t)(b * S_) + qb2[u] + 4 * g + reg) * DM_ + h * 64;
#pragma unroll
      for (int n = 0; n < 4; ++n) {
        const float val = __fmul_rn(oacc[u][n][reg] / L, sv);
        ao[orow + n * 16 + c] = val;
        am = fmaxf(am, fabsf(val));
      }
    }
  }
#pragma unroll
  for (int off = 1; off <= 32; off <<= 1) am = fmaxf(am, __shfl_xor(am, off));
  if (lane == 0) atomicMax(amax_out, __float_as_uint(am));
}

extern "C" void kernel_launch(void* const* d_in, const int* in_sizes, int n_in,
                              void* d_out, int out_size, void* d_ws, size_t ws_size,
                              hipStream_t stream) {
  const float* inputs_q  = (const float*)d_in[0];
  const float* inputs_kv = (const float*)d_in[1];
  const float* Wq = (const float*)d_in[2];
  const float* bq = (const float*)d_in[3];
  const float* Wk = (const float*)d_in[4];
  const float* bk = (const float*)d_in[5];
  const float* Wv = (const float*)d_in[6];
  const float* bv = (const float*)d_in[7];
  const float* Wo = (const float*)d_in[8];
  const float* bo = (const float*)d_in[9];
  const float* rel = (const float*)d_in[10];
  float* out = (float*)d_out;

  char* ws = (char*)d_ws;
  constexpr size_t MB = 1024 * 1024;
  // slots: 0 sx_q, 1 sx_kv, 2 sWq, 3 sWk, 4 sWv, 5 sWo, 6 sq, 7 sk, 8 sv, 9 sao
  unsigned* slots = (unsigned*)ws;
  u16* xq_b  = (u16*)(ws + 1024);
  u16* xkv_b = (u16*)((char*)xq_b + 8 * MB);
  u16* wq_b  = (u16*)((char*)xkv_b + 8 * MB);
  u16* wk_b  = (u16*)((char*)wq_b + 2 * MB);
  u16* wv_b  = (u16*)((char*)wk_b + 2 * MB);
  u16* wo_b  = (u16*)((char*)wv_b + 2 * MB);
  u16* q_p   = (u16*)((char*)wo_b + 2 * MB);  // [bh][s][64] contiguous panels
  u16* k_p   = (u16*)((char*)q_p + 8 * MB);   // [bh][s][64]
  u16* vT_b  = (u16*)((char*)k_p + 8 * MB);   // [bh*64+d][kv]
  u16* ao_b  = (u16*)((char*)vT_b + 8 * MB);
  float* tf  = (float*)((char*)ao_b + 8 * MB);  // 16 MB f32 scratch
  (void)ws_size; (void)in_sizes; (void)n_in; (void)out_size;

  const int n4_x = (B_ * S_ * DM_) / 4, n4_w = (DM_ * DM_) / 4;
  const int n8_x = (B_ * S_ * DM_) / 8;

  zero_slots_kernel<<<1, 64, 0, stream>>>(slots);

  Ptr6 a6;
  a6.p[0] = inputs_q;  a6.n4[0] = n4_x;
  a6.p[1] = inputs_kv; a6.n4[1] = n4_x;
  a6.p[2] = Wq; a6.n4[2] = n4_w;
  a6.p[3] = Wk; a6.n4[3] = n4_w;
  a6.p[4] = Wv; a6.n4[4] = n4_w;
  a6.p[5] = Wo; a6.n4[5] = n4_w;
  absmax6_kernel<<<dim3(128, 6), 256, 0, stream>>>(a6, slots);

  quantize2_kernel<<<dim3(512, 2), 256, 0, stream>>>(inputs_q, inputs_kv, xq_b, xkv_b,
                                                     slots, n8_x);
  W4 w4;
  w4.w[0] = Wq; w4.wt[0] = wq_b;
  w4.w[1] = Wk; w4.wt[1] = wk_b;
  w4.w[2] = Wv; w4.wt[2] = wv_b;
  w4.w[3] = Wo; w4.wt[3] = wo_b;
  quantW4_kernel<<<dim3(16, 16, 4), 256, 0, stream>>>(w4, slots);

  gemm128_kernel<<<512, 256, 0, stream>>>(xq_b, wq_b, slots + 0, slots + 2, bq, tf, slots + 6);
  quantizeP_kernel<<<1024, 256, 0, stream>>>(tf, slots + 6, q_p);
  gemm128_kernel<<<512, 256, 0, stream>>>(xkv_b, wk_b, slots + 1, slots + 3, bk, tf, slots + 7);
  quantizeP_kernel<<<1024, 256, 0, stream>>>(tf, slots + 7, k_p);
  gemm128_kernel<<<512, 256, 0, stream>>>(xkv_b, wv_b, slots + 1, slots + 4, bv, tf, slots + 8);
  quantizeT_v_kernel<<<dim3(64, 16), 256, 0, stream>>>(tf, slots + 8, vT_b);

  attn_kernel<<<512, 256, 0, stream>>>(q_p, k_p, vT_b, slots, rel, tf, slots + 9);

  quantize_bf16_kernel<<<1024, 256, 0, stream>>>(tf, n8_x, slots + 9, ao_b);

  gemm128_kernel<<<512, 256, 0, stream>>>(ao_b, wo_b, slots + 9, slots + 5, bo, out, nullptr);
}